// Round 1
// baseline (117.353 us; speedup 1.0000x reference)
//
#include <hip/hip_runtime.h>
#include <math.h>

// Problem constants (fixed by setup_inputs): B=4, N=2048, C=32
#define NB 4
#define NA 2048
#define NC 32
#define JT 128          // j-tile staged in LDS per block
#define IT 256          // i per block (= block size)

static constexpr float CONV001 = 3.3207156f;   // 332.07156 * 0.01

// ws layout (floats):
//   [0, NB*NA)          s_i per atom
//   [NB*NA, 2*NB*NA)    s_j per atom
//   [2*NB*NA + b]       self_acc[b]   (b < NB)
//   [2*NB*NA + NB + b]  pair_acc[b]
#define WS_SI  0
#define WS_SJ  (NB * NA)
#define WS_SELF (2 * NB * NA)
#define WS_PAIR (2 * NB * NA + NB)

__device__ __forceinline__ float block_reduce_sum(float v) {
    // wave-64 butterfly then cross-wave via LDS (block = 256 threads = 4 waves)
    #pragma unroll
    for (int off = 32; off > 0; off >>= 1)
        v += __shfl_down(v, off, 64);
    __shared__ float wsum[4];
    int lane = threadIdx.x & 63;
    int w = threadIdx.x >> 6;
    if (lane == 0) wsum[w] = v;
    __syncthreads();
    float r = 0.f;
    if (threadIdx.x == 0)
        r = wsum[0] + wsum[1] + wsum[2] + wsum[3];
    return r;  // valid on thread 0 only
}

// Pass 1: per-atom dot products + E_self reduction.
// grid = NB*NA/256 = 32 blocks of 256; each block lies within one batch.
__global__ void atom_kernel(const float* __restrict__ embs,
                            const float* __restrict__ qs,
                            const float* __restrict__ born,
                            const float* __restrict__ die,
                            const float* __restrict__ sf,
                            float* __restrict__ ws) {
    int a = blockIdx.x * blockDim.x + threadIdx.x;   // 0..8191
    int b = a >> 11;                                  // / NA
    const float* e = embs + (size_t)a * NC;
    float si = 0.f, sj = 0.f, ad = 0.f, R = 0.f;
    #pragma unroll
    for (int c = 0; c < NC; ++c) {
        float ev = e[c];
        si += ev * sf[c];
        sj += ev * sf[NC + c];
        ad += ev * die[c];
        R  += ev * born[c];
    }
    ad += 1e-6f;
    R  += 1.0f;
    ws[WS_SI + a] = si;
    ws[WS_SJ + a] = sj;
    float eself = -(1.0f - 1.0f / ad) * qs[a] / (R + 1e-6f);
    float bs = block_reduce_sum(eself);
    if (threadIdx.x == 0)
        atomicAdd(&ws[WS_SELF + b], bs);
}

// Pass 2: N^2 pair energy. grid = (N/JT, N/IT, NB), block = IT = 256.
__global__ void __launch_bounds__(IT)
pair_kernel(const float* __restrict__ X,
            const float* __restrict__ sf,
            float* __restrict__ ws) {
    int b  = blockIdx.z;
    int i  = blockIdx.y * IT + threadIdx.x;
    int j0 = blockIdx.x * JT;
    const float wd = sf[2 * NC];

    const float* Xb = X + (size_t)b * NA * 3;
    float xi = Xb[i * 3 + 0];
    float yi = Xb[i * 3 + 1];
    float zi = Xb[i * 3 + 2];
    float si = ws[WS_SI + b * NA + i];

    __shared__ float xj[JT], yj[JT], zj[JT], sjs[JT];
    int t = threadIdx.x;
    if (t < JT) {
        int j = j0 + t;
        xj[t]  = Xb[j * 3 + 0];
        yj[t]  = Xb[j * 3 + 1];
        zj[t]  = Xb[j * 3 + 2];
        sjs[t] = ws[WS_SJ + b * NA + j];
    }
    __syncthreads();

    float acc = 0.f;
    #pragma unroll 8
    for (int jj = 0; jj < JT; ++jj) {
        float dx = xj[jj] - xi;
        float dy = yj[jj] - yi;
        float dz = zj[jj] - zi;
        // reference adds 1e-6 to each of the 3 squared components
        float d2 = fmaf(dx, dx, fmaf(dy, dy, fmaf(dz, dz, 3e-6f)));
        float D    = __builtin_amdgcn_sqrtf(d2);
        float invD = __builtin_amdgcn_rcpf(D + 1e-6f);
        acc += invD * fmaf(wd, D, si + sjs[jj]);
    }

    float bs = block_reduce_sum(acc);
    if (t == 0)
        atomicAdd(&ws[WS_PAIR + b], bs);
}

// Pass 3: combine + NaN guard.
__global__ void finalize_kernel(const float* __restrict__ ws,
                                float* __restrict__ out) {
    int b = threadIdx.x;
    if (b < NB) {
        float v = CONV001 * (ws[WS_SELF + b] + 0.5f * ws[WS_PAIR + b]);
        out[b] = isnan(v) ? 1e-6f : v;
    }
}

extern "C" void kernel_launch(void* const* d_in, const int* in_sizes, int n_in,
                              void* d_out, int out_size, void* d_ws, size_t ws_size,
                              hipStream_t stream) {
    const float* X    = (const float*)d_in[0];
    const float* embs = (const float*)d_in[1];
    const float* qs   = (const float*)d_in[2];
    // d_in[3] = paired_mask (unused by reference)
    const float* born = (const float*)d_in[4];
    const float* die  = (const float*)d_in[5];
    const float* sf   = (const float*)d_in[6];
    float* ws  = (float*)d_ws;
    float* out = (float*)d_out;

    // zero the 8 accumulator slots (ws is poisoned each call)
    hipMemsetAsync(ws + WS_SELF, 0, 2 * NB * sizeof(float), stream);

    atom_kernel<<<NB * NA / 256, 256, 0, stream>>>(embs, qs, born, die, sf, ws);
    pair_kernel<<<dim3(NA / JT, NA / IT, NB), IT, 0, stream>>>(X, sf, ws);
    finalize_kernel<<<1, 64, 0, stream>>>(ws, out);
}